// Round 1
// baseline (399.183 us; speedup 1.0000x reference)
//
#include <hip/hip_runtime.h>

// Contrastive loss, B=8192, D=128, 100 classes, margin=2.
// loss = [ sum_{i!=j, same} d2_ij + sum_{i!=j, diff} max(2 - d_ij, 0)^2 ] / (B*(B-1))
// Symmetric in (i,j): compute i<j only, double at the end.

#define BN 8192
#define DD 128
#define TILE 64
#define KC 32

__global__ void sq_kernel(const float* __restrict__ f, float* __restrict__ sq) {
    int idx = blockIdx.x * blockDim.x + threadIdx.x;
    int row = idx >> 6;
    int lane = idx & 63;
    if (row >= BN) return;
    float2 v = ((const float2*)(f + (size_t)row * DD))[lane];
    float s = v.x * v.x + v.y * v.y;
#pragma unroll
    for (int off = 32; off > 0; off >>= 1) s += __shfl_down(s, off, 64);
    if (lane == 0) sq[row] = s;
}

__global__ __launch_bounds__(256) void pair_kernel(
        const float* __restrict__ f, const int* __restrict__ labels,
        const float* __restrict__ sq, float* __restrict__ acc) {
    const int bx = blockIdx.x, by = blockIdx.y;
    if (bx < by) return;                 // upper triangle of 128x128 tile grid
    const int i0 = by * TILE, j0 = bx * TILE;

    __shared__ float a_s[KC][TILE];      // [k][i] transposed for broadcast reads
    __shared__ float b_s[KC][TILE];

    const int tid = threadIdx.x;         // 256 threads = 16x16
    const int tx = tid & 15, ty = tid >> 4;

    float dot[4][4];
#pragma unroll
    for (int a = 0; a < 4; a++)
#pragma unroll
        for (int b = 0; b < 4; b++) dot[a][b] = 0.f;

    for (int k0 = 0; k0 < DD; k0 += KC) {
        __syncthreads();
#pragma unroll
        for (int q = 0; q < 2; q++) {
            int e = tid + q * 256;       // 512 float4 slots: 64 rows x 8 float4-cols
            int r = e >> 3;
            int c = (e & 7) << 2;
            float4 va = *(const float4*)(f + (size_t)(i0 + r) * DD + k0 + c);
            a_s[c + 0][r] = va.x; a_s[c + 1][r] = va.y;
            a_s[c + 2][r] = va.z; a_s[c + 3][r] = va.w;
            float4 vb = *(const float4*)(f + (size_t)(j0 + r) * DD + k0 + c);
            b_s[c + 0][r] = vb.x; b_s[c + 1][r] = vb.y;
            b_s[c + 2][r] = vb.z; b_s[c + 3][r] = vb.w;
        }
        __syncthreads();
#pragma unroll
        for (int k = 0; k < KC; k++) {
            float4 av = *(const float4*)&a_s[k][ty << 2];
            float4 bv = *(const float4*)&b_s[k][tx << 2];
            float ar[4] = {av.x, av.y, av.z, av.w};
            float br[4] = {bv.x, bv.y, bv.z, bv.w};
#pragma unroll
            for (int ii = 0; ii < 4; ii++)
#pragma unroll
                for (int jj = 0; jj < 4; jj++)
                    dot[ii][jj] = fmaf(ar[ii], br[jj], dot[ii][jj]);
        }
    }

    // epilogue: per-pair loss terms (i<j only)
    float sqi[4], sqj[4];
    int li[4], lj[4];
#pragma unroll
    for (int ii = 0; ii < 4; ii++) {
        int gi = i0 + (ty << 2) + ii;
        sqi[ii] = sq[gi]; li[ii] = labels[gi];
    }
#pragma unroll
    for (int jj = 0; jj < 4; jj++) {
        int gj = j0 + (tx << 2) + jj;
        sqj[jj] = sq[gj]; lj[jj] = labels[gj];
    }

    float pos = 0.f, neg = 0.f, cnt = 0.f;
#pragma unroll
    for (int ii = 0; ii < 4; ii++) {
        int gi = i0 + (ty << 2) + ii;
#pragma unroll
        for (int jj = 0; jj < 4; jj++) {
            int gj = j0 + (tx << 2) + jj;
            if (gi < gj) {
                float d2 = fmaxf(sqi[ii] + sqj[jj] - 2.f * dot[ii][jj], 0.f);
                if (li[ii] == lj[jj]) {
                    pos += d2; cnt += 1.f;
                } else if (d2 < 4.0f) {   // hinge active iff d < margin
                    float h = 2.0f - sqrtf(d2);
                    neg += h * h;
                }
            }
        }
    }

    // block reduction: wave shuffle, then LDS across 4 waves, one atomic set/block
#pragma unroll
    for (int off = 32; off > 0; off >>= 1) {
        pos += __shfl_down(pos, off, 64);
        neg += __shfl_down(neg, off, 64);
        cnt += __shfl_down(cnt, off, 64);
    }
    __shared__ float red[3][4];
    int lane = tid & 63, w = tid >> 6;
    if (lane == 0) { red[0][w] = pos; red[1][w] = neg; red[2][w] = cnt; }
    __syncthreads();
    if (tid == 0) {
        float p = red[0][0] + red[0][1] + red[0][2] + red[0][3];
        float n = red[1][0] + red[1][1] + red[1][2] + red[1][3];
        float c = red[2][0] + red[2][1] + red[2][2] + red[2][3];
        atomicAdd(&acc[0], p);
        atomicAdd(&acc[1], n);
        atomicAdd(&acc[2], c);
    }
}

__global__ void finalize_kernel(const float* __restrict__ acc, float* __restrict__ out) {
    if (threadIdx.x == 0 && blockIdx.x == 0) {
        float total = 2.0f * (acc[0] + acc[1]);   // unordered -> ordered pairs
        float cnt = acc[2];
        out[0] = (cnt > 0.f) ? total / 67100672.0f : total;  // B*(B-1)
    }
}

extern "C" void kernel_launch(void* const* d_in, const int* in_sizes, int n_in,
                              void* d_out, int out_size, void* d_ws, size_t ws_size,
                              hipStream_t stream) {
    const float* f = (const float*)d_in[0];
    const int* labels = (const int*)d_in[1];
    float* out = (float*)d_out;
    float* ws = (float*)d_ws;
    float* sq = ws;              // BN floats
    float* acc = ws + BN;        // 3 floats: pos, neg, cnt

    hipMemsetAsync(acc, 0, 3 * sizeof(float), stream);
    sq_kernel<<<BN * 64 / 256, 256, 0, stream>>>(f, sq);
    dim3 grid(BN / TILE, BN / TILE);
    pair_kernel<<<grid, 256, 0, stream>>>(f, labels, sq, acc);
    finalize_kernel<<<1, 64, 0, stream>>>(acc, out);
}

// Round 2
// 165.763 us; speedup vs baseline: 2.4082x; 2.4082x over previous
//
#include <hip/hip_runtime.h>
#include <hip/hip_bf16.h>

// Contrastive loss, B=8192, D=128, 100 classes, margin=2.
// Gram matrix via bf16 MFMA (16x16x32): for F*F^T both A and B fragments
// load identically from F (B[k][n]=F[n][k] == A-layout of the j-tile).
// Symmetric in (i,j): compute i<j only (upper-triangle tile grid), double.

#define BN 8192
#define DD 128

typedef __attribute__((ext_vector_type(8))) short bf16x8;   // 8 bf16 = 4 VGPRs
typedef __attribute__((ext_vector_type(4))) float f32x4;

// fp32 -> bf16 (RN) conversion + row squared-norms (from the rounded values,
// so d2 is the exact distance of the rounded vectors).
__global__ __launch_bounds__(256) void prep_kernel(const float* __restrict__ f,
        __hip_bfloat16* __restrict__ fb, float* __restrict__ sq) {
    int idx = blockIdx.x * blockDim.x + threadIdx.x;  // BN*64 threads
    int row = idx >> 6, lane = idx & 63;
    float2 v = ((const float2*)(f + (size_t)row * DD))[lane];
    __hip_bfloat162 b2;
    b2.x = __float2bfloat16(v.x);
    b2.y = __float2bfloat16(v.y);
    ((__hip_bfloat162*)(fb + (size_t)row * DD))[lane] = b2;
    float xr = __bfloat162float(b2.x), yr = __bfloat162float(b2.y);
    float s = xr * xr + yr * yr;
#pragma unroll
    for (int off = 32; off > 0; off >>= 1) s += __shfl_down(s, off, 64);
    if (lane == 0) sq[row] = s;
}

__global__ __launch_bounds__(256) void pair_kernel(
        const __hip_bfloat16* __restrict__ fb, const int* __restrict__ labels,
        const float* __restrict__ sq, float* __restrict__ acc) {
    const int bx = blockIdx.x, by = blockIdx.y;
    if (bx < by) return;                       // upper triangle of 64x64 tile grid
    const int tid = threadIdx.x;
    const int wave = tid >> 6, lane = tid & 63;
    const int wx = wave & 1, wy = wave >> 1;   // 2x2 waves over the 128x128 block
    const int i0 = by * 128 + wy * 64;
    const int j0 = bx * 128 + wx * 64;
    const int l15 = lane & 15, quad = lane >> 4;

    f32x4 acc4[4][4];
#pragma unroll
    for (int a = 0; a < 4; a++)
#pragma unroll
        for (int b = 0; b < 4; b++) acc4[a][b] = (f32x4){0.f, 0.f, 0.f, 0.f};

    // K = 128 = 4 k-steps of 32. Fragment: 16B load per lane, direct from L2.
#pragma unroll
    for (int ks = 0; ks < 4; ks++) {
        bf16x8 af[4], bg[4];
        const int kofs = ks * 32 + quad * 8;
#pragma unroll
        for (int t = 0; t < 4; t++)
            af[t] = *(const bf16x8*)(fb + (size_t)(i0 + t * 16 + l15) * DD + kofs);
#pragma unroll
        for (int t = 0; t < 4; t++)
            bg[t] = *(const bf16x8*)(fb + (size_t)(j0 + t * 16 + l15) * DD + kofs);
#pragma unroll
        for (int mi = 0; mi < 4; mi++)
#pragma unroll
            for (int ni = 0; ni < 4; ni++)
                acc4[mi][ni] = __builtin_amdgcn_mfma_f32_16x16x32_bf16(
                    af[mi], bg[ni], acc4[mi][ni], 0, 0, 0);
    }

    // Epilogue. C/D layout: col = lane&15 (j side), row = quad*4 + reg (i side).
    float sqj[4]; int lj[4];
#pragma unroll
    for (int ni = 0; ni < 4; ni++) {
        int gj = j0 + ni * 16 + l15;
        sqj[ni] = sq[gj]; lj[ni] = labels[gj];
    }
    float sqi[4][4]; int li[4][4];
#pragma unroll
    for (int mi = 0; mi < 4; mi++)
#pragma unroll
        for (int r = 0; r < 4; r++) {
            int gi = i0 + mi * 16 + quad * 4 + r;
            sqi[mi][r] = sq[gi]; li[mi][r] = labels[gi];
        }

    float pos = 0.f, neg = 0.f, cnt = 0.f;
#pragma unroll
    for (int mi = 0; mi < 4; mi++)
#pragma unroll
        for (int ni = 0; ni < 4; ni++)
#pragma unroll
            for (int r = 0; r < 4; r++) {
                float dot = acc4[mi][ni][r];
                int gi = i0 + mi * 16 + quad * 4 + r;
                int gj = j0 + ni * 16 + l15;
                bool valid = gi < gj;          // always true for bx>by blocks
                float d2 = fmaxf(sqi[mi][r] + sqj[ni] - 2.f * dot, 0.f);
                bool same = li[mi][r] == lj[ni];
                if (valid && same) { pos += d2; cnt += 1.f; }
                else if (valid && d2 < 4.0f) { // hinge active iff d < margin (rare)
                    float h = 2.0f - sqrtf(d2);
                    neg += h * h;
                }
            }

    // block reduction: wave shuffle, LDS across 4 waves, one atomic set/block
#pragma unroll
    for (int off = 32; off > 0; off >>= 1) {
        pos += __shfl_down(pos, off, 64);
        neg += __shfl_down(neg, off, 64);
        cnt += __shfl_down(cnt, off, 64);
    }
    __shared__ float red[3][4];
    if (lane == 0) { red[0][wave] = pos; red[1][wave] = neg; red[2][wave] = cnt; }
    __syncthreads();
    if (tid == 0) {
        atomicAdd(&acc[0], red[0][0] + red[0][1] + red[0][2] + red[0][3]);
        atomicAdd(&acc[1], red[1][0] + red[1][1] + red[1][2] + red[1][3]);
        atomicAdd(&acc[2], red[2][0] + red[2][1] + red[2][2] + red[2][3]);
    }
}

__global__ void finalize_kernel(const float* __restrict__ acc, float* __restrict__ out) {
    if (threadIdx.x == 0 && blockIdx.x == 0) {
        float total = 2.0f * (acc[0] + acc[1]);   // unordered -> ordered pairs
        float cnt = acc[2];
        out[0] = (cnt > 0.f) ? total / 67100672.0f : total;  // B*(B-1)
    }
}

extern "C" void kernel_launch(void* const* d_in, const int* in_sizes, int n_in,
                              void* d_out, int out_size, void* d_ws, size_t ws_size,
                              hipStream_t stream) {
    const float* f = (const float*)d_in[0];
    const int* labels = (const int*)d_in[1];
    float* out = (float*)d_out;

    // workspace layout: bf16 features (2 MB) | sq (32 KB) | acc (3 floats)
    __hip_bfloat16* fb = (__hip_bfloat16*)d_ws;
    float* sq = (float*)((char*)d_ws + (size_t)BN * DD * sizeof(__hip_bfloat16));
    float* acc = sq + BN;

    hipMemsetAsync(acc, 0, 3 * sizeof(float), stream);
    prep_kernel<<<BN * 64 / 256, 256, 0, stream>>>(f, fb, sq);
    dim3 grid(BN / 128, BN / 128);
    pair_kernel<<<grid, 256, 0, stream>>>(fb, labels, sq, acc);
    finalize_kernel<<<1, 64, 0, stream>>>(acc, out);
}